// Round 8
// baseline (121.434 us; speedup 1.0000x reference)
//
#include <hip/hip_runtime.h>

#define T_STEPS 1024
#define B_ELEMS 32768
#define K_CKPT 8
#define NS (T_STEPS / K_CKPT)     // 128 stored steps per pass-2 thread
#define STEP 0.5f

typedef float f32x4 __attribute__((ext_vector_type(4)));

#define ADVANCE()                                  \
    do {                                           \
        float bSI = bb * S * I;                    \
        float sE  = ss * E;                        \
        float gI  = gg * I;                        \
        float Sn = S - bSI * STEP;                 \
        float En = E + (bSI - sE) * STEP;          \
        float In = I + (sE - gI) * STEP;           \
        float Rn = R + gI * STEP;                  \
        S = Sn; E = En; I = In; R = Rn;            \
    } while (0)

// Pass 1: B threads walk the chain once, dropping K checkpoint states into ws.
// ws layout: ws[(k*4 + var)*B + b]  (coalesced per var).
__global__ __launch_bounds__(64) void seir_ckpt_kernel(
    const float* __restrict__ initial,
    const float* __restrict__ beta,
    const float* __restrict__ gamma,
    const float* __restrict__ sigma,
    float* __restrict__ ws)
{
    constexpr int B = B_ELEMS;
    const int b = blockIdx.x * 64 + threadIdx.x;

    const float bb = beta[0];
    const float gg = gamma[0];
    const float ss = sigma[0];

    float S = initial[0 * B + b];
    float E = initial[1 * B + b];
    float I = initial[2 * B + b];
    float R = initial[3 * B + b];

    for (int k = 0; k < K_CKPT; ++k) {
        ws[(k * 4 + 0) * B + b] = S;
        ws[(k * 4 + 1) * B + b] = E;
        ws[(k * 4 + 2) * B + b] = I;
        ws[(k * 4 + 3) * B + b] = R;
        if (k < K_CKPT - 1) {
            for (int i = 0; i < NS; ++i) ADVANCE();
        }
    }
}

// Pass 2: B*K threads; thread (b,k) resumes from checkpoint k and stores its
// 128 rows. Short chains + 16 waves/CU -> fill-kernel-like store regime.
__global__ __launch_bounds__(256) void seir_store_kernel(
    const float* __restrict__ beta,
    const float* __restrict__ gamma,
    const float* __restrict__ sigma,
    const float* __restrict__ ws,
    f32x4* __restrict__ out)
{
    constexpr int B = B_ELEMS;
    constexpr int BLOCKS_PER_K = B / 256;          // 128
    const int k = blockIdx.x / BLOCKS_PER_K;       // slow index: concurrent
    const int b = (blockIdx.x % BLOCKS_PER_K) * 256 + threadIdx.x;

    const float bb = beta[0];
    const float gg = gamma[0];
    const float ss = sigma[0];

    float S = ws[(k * 4 + 0) * B + b];
    float E = ws[(k * 4 + 1) * B + b];
    float I = ws[(k * 4 + 2) * B + b];
    float R = ws[(k * 4 + 3) * B + b];

    size_t idx = (size_t)k * NS * B + b;
    for (int n = 0; n < NS; ++n, idx += B) {
        f32x4 v = {S, E, I, R};
        __builtin_nontemporal_store(v, &out[idx]);
        ADVANCE();
    }
}

// Fallback (proven 92.4 us): single-pass dep-chained NT stream.
__global__ __launch_bounds__(64) void seir_euler_kernel(
    const float* __restrict__ initial,
    const float* __restrict__ beta,
    const float* __restrict__ gamma,
    const float* __restrict__ sigma,
    f32x4* __restrict__ out)
{
    constexpr int B = B_ELEMS;
    const int b = blockIdx.x * 64 + threadIdx.x;

    const float bb = beta[0];
    const float gg = gamma[0];
    const float ss = sigma[0];

    float S = initial[0 * B + b];
    float E = initial[1 * B + b];
    float I = initial[2 * B + b];
    float R = initial[3 * B + b];

    size_t idx = (size_t)b;
    for (int n = 0; n < T_STEPS; ++n, idx += B) {
        f32x4 v = {S, E, I, R};
        __builtin_nontemporal_store(v, &out[idx]);
        ADVANCE();
    }
}

extern "C" void kernel_launch(void* const* d_in, const int* in_sizes, int n_in,
                              void* d_out, int out_size, void* d_ws, size_t ws_size,
                              hipStream_t stream)
{
    const float* initial = (const float*)d_in[0];
    const float* beta    = (const float*)d_in[1];
    const float* gamma   = (const float*)d_in[2];
    const float* sigma   = (const float*)d_in[3];
    f32x4* out = (f32x4*)d_out;

    const size_t ws_needed = (size_t)K_CKPT * 4 * B_ELEMS * sizeof(float); // 4 MiB
    if (ws_size >= ws_needed) {
        float* ws = (float*)d_ws;
        seir_ckpt_kernel<<<B_ELEMS / 64, 64, 0, stream>>>(initial, beta, gamma, sigma, ws);
        dim3 grid2((B_ELEMS / 256) * K_CKPT);      // 1024 blocks, k = slow index
        seir_store_kernel<<<grid2, 256, 0, stream>>>(beta, gamma, sigma, ws, out);
    } else {
        seir_euler_kernel<<<B_ELEMS / 64, 64, 0, stream>>>(initial, beta, gamma, sigma, out);
    }
}

// Round 9
// 96.370 us; speedup vs baseline: 1.2601x; 1.2601x over previous
//
#include <hip/hip_runtime.h>

#define T_STEPS 1024
#define B_ELEMS 32768
#define STEP 0.5f

typedef float f32x4 __attribute__((ext_vector_type(4)));

// Best configuration (R2, 92.37 us = ~6.3 TB/s steady-state store BW):
// - one thread per batch element, serial dep-chained Euler recurrence
// - nontemporal dwordx4 stores (bypass L2 allocate; plain stores were +6 us)
// - 512 waves = 2 waves/CU (every higher occupancy variant regressed:
//   NT@8w/CU +11 us, plain@4w/CU +15 us, two-pass ckpt@16w/CU +29 us)
// - no unroll / no store batching (unroll8 +4 us, burst-8 +1.2 us neutral)
__global__ __launch_bounds__(64) void seir_euler_kernel(
    const float* __restrict__ initial,   // (4, B)
    const float* __restrict__ beta,
    const float* __restrict__ gamma,
    const float* __restrict__ sigma,
    f32x4* __restrict__ out)             // (T*B) rows of 4 floats
{
    constexpr int B = B_ELEMS;
    const int b = blockIdx.x * 64 + threadIdx.x;

    const float bb = beta[0];
    const float gg = gamma[0];
    const float ss = sigma[0];

    float S = initial[0 * B + b];
    float E = initial[1 * B + b];
    float I = initial[2 * B + b];
    float R = initial[3 * B + b];

    size_t idx = (size_t)b;
    for (int n = 0; n < T_STEPS; ++n, idx += B) {
        f32x4 v = {S, E, I, R};
        __builtin_nontemporal_store(v, &out[idx]);
        float bSI = bb * S * I;
        float sE  = ss * E;
        float gI  = gg * I;
        float Sn = S - bSI * STEP;
        float En = E + (bSI - sE) * STEP;
        float In = I + (sE - gI) * STEP;
        float Rn = R + gI * STEP;
        S = Sn; E = En; I = In; R = Rn;
    }
}

extern "C" void kernel_launch(void* const* d_in, const int* in_sizes, int n_in,
                              void* d_out, int out_size, void* d_ws, size_t ws_size,
                              hipStream_t stream)
{
    const float* initial = (const float*)d_in[0];
    const float* beta    = (const float*)d_in[1];
    const float* gamma   = (const float*)d_in[2];
    const float* sigma   = (const float*)d_in[3];
    f32x4* out = (f32x4*)d_out;

    const int block = 64;                     // 512 waves -> 2 per CU, all CUs
    const int grid = B_ELEMS / block;         // 512 blocks
    seir_euler_kernel<<<grid, block, 0, stream>>>(initial, beta, gamma, sigma, out);
}